// Round 1
// baseline (2399.355 us; speedup 1.0000x reference)
//
#include <hip/hip_runtime.h>

#define NVN 20000
#define NCN 20000
#define NE  500000
#define HID 64
#define NLAYER 3

__device__ __forceinline__ float relu_(float x) { return fmaxf(x, 0.0f); }

// ---------------- Encoder: h = relu(cat([x@ew+eb, 0.5*(pe_mlp(pe)+pe_mlp(-pe))]))
// wave per node; lane j = output feature j
__global__ __launch_bounds__(256) void encode_kernel(
    const float* __restrict__ x,   // [N,2]
    const float* __restrict__ pe,  // [N,8]
    const float* __restrict__ ew,  // [2,32]
    const float* __restrict__ eb,  // [32]
    const float* __restrict__ pw1, // [8,64]
    const float* __restrict__ pb1, // [64]
    const float* __restrict__ pw2, // [64,32]
    const float* __restrict__ pb2, // [32]
    float* __restrict__ out,       // [N,64]
    int N)
{
    int wave = threadIdx.x >> 6, lane = threadIdx.x & 63;
    int n = blockIdx.x * 4 + wave;
    if (n >= N) return;

    // pe hidden (unit = lane) for +pe and -pe
    float accp = pb1[lane], accm = pb1[lane];
#pragma unroll
    for (int k = 0; k < 8; ++k) {
        float p = pe[n * 8 + k];
        float w = pw1[k * 64 + lane];
        accp += p * w;
        accm -= p * w;
    }
    float hs = 0.5f * (relu_(accp) + relu_(accm));

    int col = lane & 31;
    // pe output for column `col` (all lanes active -> shfl valid)
    float peo = pb2[col];
#pragma unroll 8
    for (int k = 0; k < 64; ++k)
        peo += __shfl(hs, k, 64) * pw2[k * 32 + col];

    float lino = x[n * 2 + 0] * ew[col] + x[n * 2 + 1] * ew[32 + col] + eb[col];
    float h = (lane < 32) ? lino : peo;
    out[n * 64 + lane] = relu_(h);
}

// ---------------- Edge pass 1: msg + atomicMax into m (m pre-zeroed; msg > 0)
__global__ __launch_bounds__(256) void edge_max_kernel(
    const float* __restrict__ xsrc, // [Nsrc,64]
    const int* __restrict__ src,    // [E]
    const int* __restrict__ dst,    // [E]
    const float* __restrict__ ewt,  // [E]
    const float* __restrict__ lew,  // [64]
    const float* __restrict__ leb,  // [64]
    float* __restrict__ m)          // [Ndst,64], init 0
{
    long long t = (long long)blockIdx.x * blockDim.x + threadIdx.x;
    int e = (int)(t >> 6);
    int lane = (int)(t & 63);
    if (e >= NE) return;
    int s = src[e], d = dst[e];
    float w = ewt[e];
    float msg = relu_(xsrc[s * 64 + lane] + w * lew[lane] + leb[lane]) + 1e-7f;
    atomicMax((int*)(m + (long long)d * 64 + lane), __float_as_int(msg));
}

// ---------------- Edge pass 2: ex = exp(msg - m[dst]); den += ex; num += ex*msg
__global__ __launch_bounds__(256) void edge_sum_kernel(
    const float* __restrict__ xsrc,
    const int* __restrict__ src,
    const int* __restrict__ dst,
    const float* __restrict__ ewt,
    const float* __restrict__ lew,
    const float* __restrict__ leb,
    const float* __restrict__ m,
    float* __restrict__ den,  // init 0
    float* __restrict__ num)  // init 0
{
    long long t = (long long)blockIdx.x * blockDim.x + threadIdx.x;
    int e = (int)(t >> 6);
    int lane = (int)(t & 63);
    if (e >= NE) return;
    int s = src[e], d = dst[e];
    float w = ewt[e];
    float msg = relu_(xsrc[s * 64 + lane] + w * lew[lane] + leb[lane]) + 1e-7f;
    float mm = m[(long long)d * 64 + lane];
    float ex = __expf(msg - mm);
    atomicAdd(den + (long long)d * 64 + lane, ex);
    atomicAdd(num + (long long)d * 64 + lane, ex * msg);
}

// ---------------- Node update: out = MLP(agg + x_dst); MLP 64->128(relu)->64
// wave per node
__global__ __launch_bounds__(256) void node_update_kernel(
    const float* __restrict__ xdst, // [N,64] previous dst features
    const float* __restrict__ den,
    const float* __restrict__ num,
    const float* __restrict__ w1, // [64,128]
    const float* __restrict__ b1, // [128]
    const float* __restrict__ w2, // [128,64]
    const float* __restrict__ b2, // [64]
    float* __restrict__ out,      // [N,64]
    int N)
{
    int wave = threadIdx.x >> 6, lane = threadIdx.x & 63;
    int n = blockIdx.x * 4 + wave;
    if (n >= N) return;

    float d = den[n * 64 + lane];
    float o = num[n * 64 + lane] / (d + 1e-16f) + xdst[n * 64 + lane];

    float h0 = b1[lane], h1 = b1[64 + lane];
#pragma unroll 8
    for (int k = 0; k < 64; ++k) {
        float ov = __shfl(o, k, 64);
        h0 += ov * w1[k * 128 + lane];
        h1 += ov * w1[k * 128 + 64 + lane];
    }
    h0 = relu_(h0);
    h1 = relu_(h1);

    float r = b2[lane];
#pragma unroll 8
    for (int k = 0; k < 64; ++k) {
        r += __shfl(h0, k, 64) * w2[k * 64 + lane];
        r += __shfl(h1, k, 64) * w2[(64 + k) * 64 + lane];
    }
    out[n * 64 + lane] = r;
}

// ---------------- Prediction head: out[n*NL+layer] = (relu(f@w1+b1))@w2 + b2
__global__ __launch_bounds__(256) void pred_kernel(
    const float* __restrict__ feat, // [N,64]
    const float* __restrict__ w1,   // [64,64]
    const float* __restrict__ b1,   // [64]
    const float* __restrict__ w2,   // [64,1]
    const float* __restrict__ b2,   // [1]
    float* __restrict__ out,        // base; write out[n*NLAYER+layer]
    int N, int layer)
{
    int wave = threadIdx.x >> 6, lane = threadIdx.x & 63;
    int n = blockIdx.x * 4 + wave;
    if (n >= N) return;

    float f = feat[n * 64 + lane];
    float h = b1[lane];
#pragma unroll 8
    for (int k = 0; k < 64; ++k)
        h += __shfl(f, k, 64) * w1[k * 64 + lane];
    h = relu_(h);

    float partial = h * w2[lane];
#pragma unroll
    for (int off = 32; off > 0; off >>= 1)
        partial += __shfl_down(partial, off, 64);
    if (lane == 0) out[n * NLAYER + layer] = partial + b2[0];
}

extern "C" void kernel_launch(void* const* d_in, const int* in_sizes, int n_in,
                              void* d_out, int out_size, void* d_ws, size_t ws_size,
                              hipStream_t stream)
{
    const float* x_vals   = (const float*)d_in[0];
    const float* x_cons   = (const float*)d_in[1];
    const float* pe_vals  = (const float*)d_in[2];
    const float* pe_cons  = (const float*)d_in[3];
    const int*   ei_v2c   = (const int*)d_in[4];   // [2,E]
    const int*   ei_c2v   = (const int*)d_in[5];   // [2,E]
    const float* ew_v2c   = (const float*)d_in[6]; // [E,1]
    const float* ew_c2v   = (const float*)d_in[7];
    const float* enc_vals_w = (const float*)d_in[8];
    const float* enc_vals_b = (const float*)d_in[9];
    const float* pe_vals_w1 = (const float*)d_in[10];
    const float* pe_vals_b1 = (const float*)d_in[11];
    const float* pe_vals_w2 = (const float*)d_in[12];
    const float* pe_vals_b2 = (const float*)d_in[13];
    const float* enc_cons_w = (const float*)d_in[14];
    const float* enc_cons_b = (const float*)d_in[15];
    const float* pe_cons_w1 = (const float*)d_in[16];
    const float* pe_cons_b1 = (const float*)d_in[17];
    const float* pe_cons_w2 = (const float*)d_in[18];
    const float* pe_cons_b2 = (const float*)d_in[19];
    const float* v2c_edge_w = (const float*)d_in[20]; // [NL,1,64]
    const float* v2c_edge_b = (const float*)d_in[21]; // [NL,64]
    const float* v2c_w1     = (const float*)d_in[22]; // [NL,64,128]
    const float* v2c_b1     = (const float*)d_in[23]; // [NL,128]
    const float* v2c_w2     = (const float*)d_in[24]; // [NL,128,64]
    const float* v2c_b2     = (const float*)d_in[25]; // [NL,64]
    const float* c2v_edge_w = (const float*)d_in[26];
    const float* c2v_edge_b = (const float*)d_in[27];
    const float* c2v_w1     = (const float*)d_in[28];
    const float* c2v_b1     = (const float*)d_in[29];
    const float* c2v_w2     = (const float*)d_in[30];
    const float* c2v_b2     = (const float*)d_in[31];
    const float* pred_vals_w1 = (const float*)d_in[32];
    const float* pred_vals_b1 = (const float*)d_in[33];
    const float* pred_vals_w2 = (const float*)d_in[34];
    const float* pred_vals_b2 = (const float*)d_in[35];
    const float* pred_cons_w1 = (const float*)d_in[36];
    const float* pred_cons_b1 = (const float*)d_in[37];
    const float* pred_cons_w2 = (const float*)d_in[38];
    const float* pred_cons_b2 = (const float*)d_in[39];

    float* out = (float*)d_out;

    // Workspace layout (floats):
    float* ws    = (float*)d_ws;
    float* enc_v = ws;                       // NV*64
    float* enc_c = enc_v + (size_t)NVN * 64; // NC*64
    float* hv    = enc_c + (size_t)NCN * 64; // NL*NV*64
    float* hc    = hv + (size_t)NLAYER * NVN * 64; // NL*NC*64
    float* mbuf  = hc + (size_t)NLAYER * NCN * 64; // 20000*64
    float* den   = mbuf + (size_t)NVN * 64;
    float* num   = den + (size_t)NVN * 64;

    const int edge_blocks = (int)(((long long)NE * 64 + 255) / 256);

    // Encoders
    encode_kernel<<<(NVN + 3) / 4, 256, 0, stream>>>(
        x_vals, pe_vals, enc_vals_w, enc_vals_b,
        pe_vals_w1, pe_vals_b1, pe_vals_w2, pe_vals_b2, enc_v, NVN);
    encode_kernel<<<(NCN + 3) / 4, 256, 0, stream>>>(
        x_cons, pe_cons, enc_cons_w, enc_cons_b,
        pe_cons_w1, pe_cons_b1, pe_cons_w2, pe_cons_b2, enc_c, NCN);

    const float* cur_v = enc_v;
    const float* cur_c = enc_c;

    for (int i = 0; i < NLAYER; ++i) {
        // ---- v2c: src = vals, dst = cons
        {
            hipMemsetAsync(mbuf, 0, (size_t)NCN * 64 * sizeof(float), stream);
            hipMemsetAsync(den, 0, (size_t)NCN * 64 * sizeof(float), stream);
            hipMemsetAsync(num, 0, (size_t)NCN * 64 * sizeof(float), stream);
            const int* src = ei_v2c;
            const int* dst = ei_v2c + NE;
            const float* lew = v2c_edge_w + (size_t)i * HID;
            const float* leb = v2c_edge_b + (size_t)i * HID;
            edge_max_kernel<<<edge_blocks, 256, 0, stream>>>(
                cur_v, src, dst, ew_v2c, lew, leb, mbuf);
            edge_sum_kernel<<<edge_blocks, 256, 0, stream>>>(
                cur_v, src, dst, ew_v2c, lew, leb, mbuf, den, num);
            float* out_c = hc + (size_t)i * NCN * 64;
            node_update_kernel<<<(NCN + 3) / 4, 256, 0, stream>>>(
                cur_c, den, num,
                v2c_w1 + (size_t)i * 64 * 128, v2c_b1 + (size_t)i * 128,
                v2c_w2 + (size_t)i * 128 * 64, v2c_b2 + (size_t)i * 64,
                out_c, NCN);
            cur_c = out_c;
        }
        // ---- c2v: src = cons, dst = vals
        {
            hipMemsetAsync(mbuf, 0, (size_t)NVN * 64 * sizeof(float), stream);
            hipMemsetAsync(den, 0, (size_t)NVN * 64 * sizeof(float), stream);
            hipMemsetAsync(num, 0, (size_t)NVN * 64 * sizeof(float), stream);
            const int* src = ei_c2v;
            const int* dst = ei_c2v + NE;
            const float* lew = c2v_edge_w + (size_t)i * HID;
            const float* leb = c2v_edge_b + (size_t)i * HID;
            edge_max_kernel<<<edge_blocks, 256, 0, stream>>>(
                cur_c, src, dst, ew_c2v, lew, leb, mbuf);
            edge_sum_kernel<<<edge_blocks, 256, 0, stream>>>(
                cur_c, src, dst, ew_c2v, lew, leb, mbuf, den, num);
            float* out_v = hv + (size_t)i * NVN * 64;
            node_update_kernel<<<(NVN + 3) / 4, 256, 0, stream>>>(
                cur_v, den, num,
                c2v_w1 + (size_t)i * 64 * 128, c2v_b1 + (size_t)i * 128,
                c2v_w2 + (size_t)i * 128 * 64, c2v_b2 + (size_t)i * 64,
                out_v, NVN);
            cur_v = out_v;
        }
    }

    // Prediction heads: out layout = [NV*NL] then [NC*NL], element [n, l] at n*NL+l
    for (int i = 0; i < NLAYER; ++i) {
        pred_kernel<<<(NVN + 3) / 4, 256, 0, stream>>>(
            hv + (size_t)i * NVN * 64, pred_vals_w1, pred_vals_b1,
            pred_vals_w2, pred_vals_b2, out, NVN, i);
        pred_kernel<<<(NCN + 3) / 4, 256, 0, stream>>>(
            hc + (size_t)i * NCN * 64, pred_cons_w1, pred_cons_b1,
            pred_cons_w2, pred_cons_b2, out + (size_t)NVN * NLAYER, NCN, i);
    }
}

// Round 2
// 897.157 us; speedup vs baseline: 2.6744x; 2.6744x over previous
//
#include <hip/hip_runtime.h>

#define NVN 20000
#define NCN 20000
#define NE  500000
#define HID 64
#define NLAYER 3

__device__ __forceinline__ float relu_(float x) { return fmaxf(x, 0.0f); }

// ---------------- Encoder: h = relu(cat([x@ew+eb, 0.5*(pe_mlp(pe)+pe_mlp(-pe))]))
// wave per node; lane j = output feature j
__global__ __launch_bounds__(256) void encode_kernel(
    const float* __restrict__ x,   // [N,2]
    const float* __restrict__ pe,  // [N,8]
    const float* __restrict__ ew,  // [2,32]
    const float* __restrict__ eb,  // [32]
    const float* __restrict__ pw1, // [8,64]
    const float* __restrict__ pb1, // [64]
    const float* __restrict__ pw2, // [64,32]
    const float* __restrict__ pb2, // [32]
    float* __restrict__ out,       // [N,64]
    int N)
{
    int wave = threadIdx.x >> 6, lane = threadIdx.x & 63;
    int n = blockIdx.x * 4 + wave;
    if (n >= N) return;

    float accp = pb1[lane], accm = pb1[lane];
#pragma unroll
    for (int k = 0; k < 8; ++k) {
        float p = pe[n * 8 + k];
        float w = pw1[k * 64 + lane];
        accp += p * w;
        accm -= p * w;
    }
    float hs = 0.5f * (relu_(accp) + relu_(accm));

    int col = lane & 31;
    float peo = pb2[col];
#pragma unroll 8
    for (int k = 0; k < 64; ++k)
        peo += __shfl(hs, k, 64) * pw2[k * 32 + col];

    float lino = x[n * 2 + 0] * ew[col] + x[n * 2 + 1] * ew[32 + col] + eb[col];
    float h = (lane < 32) ? lino : peo;
    out[n * 64 + lane] = relu_(h);
}

// ---------------- CSR build: histogram, scan, scatter ----------------
__global__ __launch_bounds__(256) void hist_kernel(
    const int* __restrict__ dst, int* __restrict__ deg)
{
    int e = blockIdx.x * blockDim.x + threadIdx.x;
    if (e < NE) atomicAdd(&deg[dst[e]], 1);
}

// single block of 1024 threads; n <= 20480
__global__ __launch_bounds__(1024) void scan_kernel(
    const int* __restrict__ deg, int* __restrict__ rowptr,
    int* __restrict__ cursor, int n)
{
    __shared__ int part[1024];
    int t = threadIdx.x;
    int chunk = (n + 1023) / 1024;
    int base = t * chunk;
    int sum = 0;
    for (int i = 0; i < chunk; ++i) {
        int idx = base + i;
        if (idx < n) sum += deg[idx];
    }
    part[t] = sum;
    __syncthreads();
    for (int off = 1; off < 1024; off <<= 1) {
        int v = (t >= off) ? part[t - off] : 0;
        __syncthreads();
        part[t] += v;
        __syncthreads();
    }
    int run = (t == 0) ? 0 : part[t - 1];
    for (int i = 0; i < chunk; ++i) {
        int idx = base + i;
        if (idx < n) {
            int d = deg[idx];
            rowptr[idx] = run;
            cursor[idx] = run;
            run += d;
        }
    }
    if (t == 1023) rowptr[n] = part[1023];
}

__global__ __launch_bounds__(256) void scatter_kernel(
    const int* __restrict__ src, const int* __restrict__ dst,
    const float* __restrict__ ewt, int* __restrict__ cursor,
    int* __restrict__ perm_src, float* __restrict__ perm_w)
{
    int e = blockIdx.x * blockDim.x + threadIdx.x;
    if (e >= NE) return;
    int pos = atomicAdd(&cursor[dst[e]], 1);
    perm_src[pos] = src[e];
    perm_w[pos] = ewt[e];
}

// ---------------- Fused GENConv: online-softmax aggregation + node MLP + pred head
// wave per dst node; lane = feature channel
__global__ __launch_bounds__(256) void conv_kernel(
    const float* __restrict__ xsrc,     // [Nsrc,64]
    const float* __restrict__ xdst,     // [Ndst,64]
    const int* __restrict__ rowptr,     // [Ndst+1]
    const int* __restrict__ perm_src,   // [E] dst-sorted
    const float* __restrict__ perm_w,   // [E]
    const float* __restrict__ lew,      // [64]
    const float* __restrict__ leb,      // [64]
    const float* __restrict__ w1,       // [64,128]
    const float* __restrict__ b1,       // [128]
    const float* __restrict__ w2,       // [128,64]
    const float* __restrict__ b2,       // [64]
    const float* __restrict__ pw1,      // [64,64] pred head
    const float* __restrict__ pb1,      // [64]
    const float* __restrict__ pw2,      // [64,1]
    const float* __restrict__ pb2,      // [1]
    float* __restrict__ outf,           // [Ndst,64] features for next layer
    float* __restrict__ outp,           // pred base: write outp[n*NLAYER+layer]
    int N, int layer)
{
    int wave = threadIdx.x >> 6, lane = threadIdx.x & 63;
    int n = blockIdx.x * 4 + wave;
    if (n >= N) return;

    int start = rowptr[n], end = rowptr[n + 1];
    float lw = lew[lane], lb = leb[lane];

    // online softmax-weighted aggregation (msg > 0 always, so m=0 is a safe init)
    float m = 0.0f, den = 0.0f, num = 0.0f;
    for (int j = start; j < end; ++j) {
        int s = perm_src[j];     // wave-uniform -> broadcast load
        float w = perm_w[j];
        float msg = relu_(xsrc[s * 64 + lane] + w * lw + lb) + 1e-7f;
        float mnew = fmaxf(m, msg);
        float c = __expf(-fabsf(msg - m));
        bool gt = msg > m;
        float c1 = gt ? c : 1.0f;
        float c2 = gt ? 1.0f : c;
        den = den * c1 + c2;
        num = num * c1 + c2 * msg;
        m = mnew;
    }
    float o = num / (den + 1e-16f) + xdst[n * 64 + lane];

    // MLP 64 -> 128 (relu) -> 64
    float h0 = b1[lane], h1 = b1[64 + lane];
#pragma unroll 8
    for (int k = 0; k < 64; ++k) {
        float ov = __shfl(o, k, 64);
        h0 += ov * w1[k * 128 + lane];
        h1 += ov * w1[k * 128 + 64 + lane];
    }
    h0 = relu_(h0);
    h1 = relu_(h1);

    float r = b2[lane];
#pragma unroll 8
    for (int k = 0; k < 64; ++k) {
        r += __shfl(h0, k, 64) * w2[k * 64 + lane];
        r += __shfl(h1, k, 64) * w2[(64 + k) * 64 + lane];
    }
    outf[n * 64 + lane] = r;

    // prediction head: (relu(r@pw1+pb1))@pw2 + pb2 -> outp[n*NLAYER+layer]
    float h = pb1[lane];
#pragma unroll 8
    for (int k = 0; k < 64; ++k)
        h += __shfl(r, k, 64) * pw1[k * 64 + lane];
    h = relu_(h);

    float partial = h * pw2[lane];
#pragma unroll
    for (int off = 32; off > 0; off >>= 1)
        partial += __shfl_down(partial, off, 64);
    if (lane == 0) outp[n * NLAYER + layer] = partial + pb2[0];
}

extern "C" void kernel_launch(void* const* d_in, const int* in_sizes, int n_in,
                              void* d_out, int out_size, void* d_ws, size_t ws_size,
                              hipStream_t stream)
{
    const float* x_vals   = (const float*)d_in[0];
    const float* x_cons   = (const float*)d_in[1];
    const float* pe_vals  = (const float*)d_in[2];
    const float* pe_cons  = (const float*)d_in[3];
    const int*   ei_v2c   = (const int*)d_in[4];   // [2,E]
    const int*   ei_c2v   = (const int*)d_in[5];   // [2,E]
    const float* ew_v2c   = (const float*)d_in[6]; // [E,1]
    const float* ew_c2v   = (const float*)d_in[7];
    const float* enc_vals_w = (const float*)d_in[8];
    const float* enc_vals_b = (const float*)d_in[9];
    const float* pe_vals_w1 = (const float*)d_in[10];
    const float* pe_vals_b1 = (const float*)d_in[11];
    const float* pe_vals_w2 = (const float*)d_in[12];
    const float* pe_vals_b2 = (const float*)d_in[13];
    const float* enc_cons_w = (const float*)d_in[14];
    const float* enc_cons_b = (const float*)d_in[15];
    const float* pe_cons_w1 = (const float*)d_in[16];
    const float* pe_cons_b1 = (const float*)d_in[17];
    const float* pe_cons_w2 = (const float*)d_in[18];
    const float* pe_cons_b2 = (const float*)d_in[19];
    const float* v2c_edge_w = (const float*)d_in[20]; // [NL,1,64]
    const float* v2c_edge_b = (const float*)d_in[21]; // [NL,64]
    const float* v2c_w1     = (const float*)d_in[22]; // [NL,64,128]
    const float* v2c_b1     = (const float*)d_in[23]; // [NL,128]
    const float* v2c_w2     = (const float*)d_in[24]; // [NL,128,64]
    const float* v2c_b2     = (const float*)d_in[25]; // [NL,64]
    const float* c2v_edge_w = (const float*)d_in[26];
    const float* c2v_edge_b = (const float*)d_in[27];
    const float* c2v_w1     = (const float*)d_in[28];
    const float* c2v_b1     = (const float*)d_in[29];
    const float* c2v_w2     = (const float*)d_in[30];
    const float* c2v_b2     = (const float*)d_in[31];
    const float* pred_vals_w1 = (const float*)d_in[32];
    const float* pred_vals_b1 = (const float*)d_in[33];
    const float* pred_vals_w2 = (const float*)d_in[34];
    const float* pred_vals_b2 = (const float*)d_in[35];
    const float* pred_cons_w1 = (const float*)d_in[36];
    const float* pred_cons_b1 = (const float*)d_in[37];
    const float* pred_cons_w2 = (const float*)d_in[38];
    const float* pred_cons_b2 = (const float*)d_in[39];

    float* out = (float*)d_out;
    float* out_c = out + (size_t)NVN * NLAYER;

    const size_t NF = (size_t)NVN * 64;  // == NCN*64

    // Workspace layout
    float* ws    = (float*)d_ws;
    float* enc_v = ws;                // NF
    float* enc_c = enc_v + NF;        // NF
    float* vbuf0 = enc_c + NF;        // NF
    float* cbuf0 = vbuf0 + NF;        // NF
    float* vbuf1 = cbuf0 + NF;        // NF
    float* cbuf1 = vbuf1 + NF;        // NF
    int* ip = (int*)(cbuf1 + NF);
    int* v2c_rowptr = ip;                  ip += NCN + 1;
    int* v2c_cursor = ip;                  ip += NCN;
    int* v2c_deg    = ip;                  ip += NCN;
    int* v2c_psrc   = ip;                  ip += NE;
    int* c2v_rowptr = ip;                  ip += NVN + 1;
    int* c2v_cursor = ip;                  ip += NVN;
    int* c2v_deg    = ip;                  ip += NVN;
    int* c2v_psrc   = ip;                  ip += NE;
    float* v2c_pw = (float*)ip;            ip += NE;
    float* c2v_pw = (float*)ip;

    const int eb256 = (NE + 255) / 256;

    // ---- CSR build (edge structure is layer-invariant) ----
    hipMemsetAsync(v2c_deg, 0, (size_t)NCN * sizeof(int), stream);
    hipMemsetAsync(c2v_deg, 0, (size_t)NVN * sizeof(int), stream);
    hist_kernel<<<eb256, 256, 0, stream>>>(ei_v2c + NE, v2c_deg);
    hist_kernel<<<eb256, 256, 0, stream>>>(ei_c2v + NE, c2v_deg);
    scan_kernel<<<1, 1024, 0, stream>>>(v2c_deg, v2c_rowptr, v2c_cursor, NCN);
    scan_kernel<<<1, 1024, 0, stream>>>(c2v_deg, c2v_rowptr, c2v_cursor, NVN);
    scatter_kernel<<<eb256, 256, 0, stream>>>(ei_v2c, ei_v2c + NE, ew_v2c,
                                              v2c_cursor, v2c_psrc, v2c_pw);
    scatter_kernel<<<eb256, 256, 0, stream>>>(ei_c2v, ei_c2v + NE, ew_c2v,
                                              c2v_cursor, c2v_psrc, c2v_pw);

    // ---- Encoders ----
    encode_kernel<<<(NVN + 3) / 4, 256, 0, stream>>>(
        x_vals, pe_vals, enc_vals_w, enc_vals_b,
        pe_vals_w1, pe_vals_b1, pe_vals_w2, pe_vals_b2, enc_v, NVN);
    encode_kernel<<<(NCN + 3) / 4, 256, 0, stream>>>(
        x_cons, pe_cons, enc_cons_w, enc_cons_b,
        pe_cons_w1, pe_cons_b1, pe_cons_w2, pe_cons_b2, enc_c, NCN);

    const float* cur_v = enc_v;
    const float* cur_c = enc_c;
    float* vping[2] = {vbuf0, vbuf1};
    float* cping[2] = {cbuf0, cbuf1};

    for (int i = 0; i < NLAYER; ++i) {
        float* new_c = cping[i & 1];
        float* new_v = vping[i & 1];
        // v2c: src = vals, dst = cons; pred head = pred_cons
        conv_kernel<<<(NCN + 3) / 4, 256, 0, stream>>>(
            cur_v, cur_c, v2c_rowptr, v2c_psrc, v2c_pw,
            v2c_edge_w + (size_t)i * HID, v2c_edge_b + (size_t)i * HID,
            v2c_w1 + (size_t)i * 64 * 128, v2c_b1 + (size_t)i * 128,
            v2c_w2 + (size_t)i * 128 * 64, v2c_b2 + (size_t)i * 64,
            pred_cons_w1, pred_cons_b1, pred_cons_w2, pred_cons_b2,
            new_c, out_c, NCN, i);
        cur_c = new_c;
        // c2v: src = cons (updated), dst = vals; pred head = pred_vals
        conv_kernel<<<(NVN + 3) / 4, 256, 0, stream>>>(
            cur_c, cur_v, c2v_rowptr, c2v_psrc, c2v_pw,
            c2v_edge_w + (size_t)i * HID, c2v_edge_b + (size_t)i * HID,
            c2v_w1 + (size_t)i * 64 * 128, c2v_b1 + (size_t)i * 128,
            c2v_w2 + (size_t)i * 128 * 64, c2v_b2 + (size_t)i * 64,
            pred_vals_w1, pred_vals_b1, pred_vals_w2, pred_vals_b2,
            new_v, out, NVN, i);
        cur_v = new_v;
    }
}